// Round 6
// baseline (337.152 us; speedup 1.0000x reference)
//
#include <hip/hip_runtime.h>
#include <math.h>

// Problem constants
constexpr int ROWS  = 19456;   // B*C*N = 16*19*64
constexpr int IN_DIM = 200;
constexpr int FREQ  = 101;     // rfft bins
constexpr int VQD   = 64;
constexpr int NEMB  = 8192;
constexpr int DFT_BLOCKS = ROWS / 8;   // 2432

typedef __attribute__((ext_vector_type(8))) short short8;   // 8 bf16 = 4 VGPRs
typedef __attribute__((ext_vector_type(4))) float floatx4;

__device__ __forceinline__ unsigned short f2bf(float v) {   // RTN-even fp32->bf16
    unsigned int u = __builtin_bit_cast(unsigned int, v);
    unsigned int r = u + 0x7fffu + ((u >> 16) & 1u);
    return (unsigned short)(r >> 16);
}
__device__ __forceinline__ float bf2f(unsigned short b) {
    unsigned int u = ((unsigned int)b) << 16;
    return __builtin_bit_cast(float, u);
}

// cis(-2*pi*r/200) with exact quarter points (bitwise-identical to the r1-validated table)
__device__ __forceinline__ void cis_exact(int r, double& c, double& s) {
    if (r == 0)        { c =  1.0; s =  0.0; }
    else if (r == 50)  { c =  0.0; s = -1.0; }
    else if (r == 100) { c = -1.0; s =  0.0; }
    else if (r == 150) { c =  0.0; s =  1.0; }
    else {
        double ang = -6.283185307179586476925286766559 * (double)r / (double)IN_DIM;
        c = cos(ang); s = sin(ang);
    }
}

// async global->LDS DMA, 16 B per lane; LDS dest = wave-uniform base + lane*16
#define GLOAD_LDS(gp, lp) __builtin_amdgcn_global_load_lds( \
    (const __attribute__((address_space(1))) unsigned int*)(gp), \
    (__attribute__((address_space(3))) unsigned int*)(lp), 16, 0, 0)

// ---------------- workspace layout ----------------
constexpr size_t align256(size_t x) { return (x + 255) & ~(size_t)255; }
constexpr size_t SZ_FB    = (size_t)2 * ROWS * VQD * sizeof(unsigned short); // bf16 feats [2][ROWS][64]
constexpr size_t OFF_FTH  = 0;
constexpr size_t OFF_FTL  = align256(OFF_FTH + SZ_FB);
constexpr size_t SZ_CBB   = (size_t)2 * NEMB * VQD * sizeof(unsigned short); // bf16 codes [2][8192][64]
constexpr size_t OFF_CBH  = align256(OFF_FTL + SZ_FB);
constexpr size_t OFF_CBL  = align256(OFF_CBH + SZ_CBB);
constexpr size_t SZ_FD    = (size_t)2 * ROWS * VQD * sizeof(double);         // feat slot (f32, oversized ok)
constexpr size_t OFF_FD   = align256(OFF_CBL + SZ_CBB);
constexpr size_t SZ_INV   = (size_t)2 * NEMB * sizeof(double);               // f64 1/||cb||
constexpr size_t OFF_INV  = align256(OFF_FD + SZ_FD);
constexpr size_t SZ_PI    = (size_t)2 * 4 * ROWS * sizeof(int);              // top-2 per 2048-chunk
constexpr size_t OFF_PI1  = align256(OFF_INV + SZ_INV);
constexpr size_t OFF_PI2  = align256(OFF_PI1 + SZ_PI);

// ---------------- 1. fused DFT/proj (blocks < 2432) + cb_prep (blocks >= 2432) ----------------
// r23: r4 (radix-4, plain launch_bounds) body restored — r5's (256,8) was a slight
// regression. f32 featF kept. dft_cb is otherwise UNTOUCHED this round: the argmax
// z-split (below) is designed to force dft_cb into the rocprof top-5 table so the
// next change is driven by its real counters instead of subtraction-modeling.
// LDS plan (20064 B):
//   [    0,  7200) xsT  f32 [n=200][r] stride 9
//   [ 7200,  8800) e0   f32 [50][8]   x0+x2+x1+x3   (q=0)
//   [ 8800, 10400) e2   f32 [50][8]   x0+x2-x1-x3   (q=2)
//   [10400, 12000) d02  f32 [50][8]   x0-x2         (q=1,3 re)
//   [12000, 13600) d13  f32 [50][8]   x3-x1         (q=1,3 im)
//   [13600, 16832) reS  f32 [k][8]: cisT (f64[101][2]) -> bgrp1 re -> final re -> amp
//   [16832, 20064) imS  f32 [k][8]: bgrp1 im -> final im -> phase
//   projection phase: accS f32 [128][8] aliases e0 base (e-arrays dead after loop)
__global__ __launch_bounds__(256) void dft_cb_kernel(
    const float* __restrict__ x, const float* __restrict__ projA, const float* __restrict__ projP,
    const float* __restrict__ cbA, const float* __restrict__ cbP,
    unsigned short* __restrict__ ftH, unsigned short* __restrict__ ftL, float* __restrict__ featF,
    unsigned short* __restrict__ cbH, unsigned short* __restrict__ cbL, double* __restrict__ invnD)
{
    __shared__ __align__(16) char smem[20064];
    const int tid = threadIdx.x;

    if (blockIdx.x >= DFT_BLOCKS) {
        // ---- cb_prep body (validated rounds 5-16, unchanged) ----
        float* tile = (float*)smem;            // 64*65*4 = 16640 B
        float* inv  = (float*)(smem + 16640);  // 256 B
        const int bid2 = blockIdx.x - DFT_BLOCKS;
        const int which = bid2 >> 7;
        const int m0 = (bid2 & 127) * 64;
        const float* cb = which ? cbP : cbA;
        for (int e = tid; e < 4096; e += 256) {
            int c = e >> 6, d = e & 63;
            tile[c * 65 + d] = cb[(size_t)(m0 + c) * VQD + d];
        }
        __syncthreads();
        if (tid < 64) {
            double s = 0.0;
            for (int d2 = 0; d2 < 64; ++d2) { double v = (double)tile[tid * 65 + d2]; s += v * v; }
            inv[tid] = (float)(1.0 / sqrt(s));
            invnD[(size_t)which * NEMB + m0 + tid] = 1.0 / sqrt(s);
        }
        __syncthreads();
        for (int e = tid; e < 4096; e += 256) {
            int c = e >> 6, d = e & 63;
            float v = tile[c * 65 + d] * inv[c];
            unsigned short hb = f2bf(v);
            unsigned short lb = f2bf(v - bf2f(hb));
            size_t o = ((size_t)which * NEMB + m0 + c) * VQD + d;
            cbH[o] = hb; cbL[o] = lb;
        }
        return;
    }

    float*  xsT  = (float*)smem;                 // [n][r] stride 9
    float*  e0S  = (float*)(smem + 7200);        // [50][8]
    float*  e2S  = (float*)(smem + 8800);
    float*  d02S = (float*)(smem + 10400);
    float*  d13S = (float*)(smem + 12000);
    float*  reS  = (float*)(smem + 13600);       // [k][8]
    float*  imS  = (float*)(smem + 16832);
    double* cisT = (double*)(smem + 13600);      // f64[101][2] = 1616 B, aliases reS (dead)
    float*  accS = (float*)(smem + 7200);        // proj partials, after e-arrays die
    const int r0 = blockIdx.x * 8;

    for (int e = tid; e < 8 * IN_DIM; e += 256) {
        int r = e / IN_DIM, n = e - r * IN_DIM;
        xsT[n * 9 + r] = x[(size_t)(r0 + r) * IN_DIM + n];
    }
    __syncthreads();

    // radix-4 prep: 4-point DFT over a (n = 50a+b), adds only, f32
    for (int e = tid; e < 50 * 8; e += 256) {
        int b = e >> 3, r = e & 7;
        float x0 = xsT[b * 9 + r];
        float x1 = xsT[(50 + b) * 9 + r];
        float x2 = xsT[(100 + b) * 9 + r];
        float x3 = xsT[(150 + b) * 9 + r];
        float s02 = x0 + x2, dd02 = x0 - x2;
        float s13 = x1 + x3, dd13 = x3 - x1;
        e0S[e]  = s02 + s13;
        e2S[e]  = s02 - s13;
        d02S[e] = dd02;
        d13S[e] = dd13;
    }
    // cis table: one f64 sincos per k, computed once per block (2 wave-calls)
    if (tid < FREQ) {
        double c, s;
        cis_exact(tid, c, s);
        cisT[tid * 2]     = c;
        cisT[tid * 2 + 1] = s;
    }
    __syncthreads();

    // q-homogeneous wave mapping: parity = wave&1 selects k parity; bgrp = wave>>1
    const int lane = tid & 63, wv = tid >> 6;
    const int parity = wv & 1, bgrp = wv >> 1;
    const int k = 2 * lane + parity;
    const bool act = (k < FREQ);                 // even wave: 51 lanes, odd: 50

    double c1 = 1.0, s1 = 0.0, wc = 1.0, ws = 0.0;
    if (act) {
        c1 = cisT[k * 2]; s1 = cisT[k * 2 + 1];
        if (bgrp) {
            // start twiddle W^{25k} = e^{-i pi (k&7)/4}: exact eighth points
            const double RH = 0.70710678118654752440;
            switch (k & 7) {
                case 0:  wc =  1.0; ws =  0.0; break;
                case 1:  wc =  RH;  ws = -RH;  break;
                case 2:  wc =  0.0; ws = -1.0; break;
                case 3:  wc = -RH;  ws = -RH;  break;
                case 4:  wc = -1.0; ws =  0.0; break;
                case 5:  wc = -RH;  ws =  RH;  break;
                case 6:  wc =  0.0; ws =  1.0; break;
                default: wc =  RH;  ws =  RH;  break;
            }
        }
    }
    __syncthreads();   // seals cisT before bgrp1's reS stores (table now dead)

    float re[8], im[8];
    if (act) {
#pragma unroll
        for (int r = 0; r < 8; ++r) { re[r] = 0.f; im[r] = 0.f; }
        const int b0 = bgrp * 25;
        if (parity == 0) {
            // even k: Y real = e0 (q=0) or e2 (q=2); 2 FMA/r, 2 b128/iter
            const float* Y = (k & 2) ? e2S : e0S;
            for (int j = 0; j < 25; ++j) {
                const float* Yb = Y + (b0 + j) * 8;
                float wcf = (float)wc, wsf = (float)ws;
#pragma unroll
                for (int r = 0; r < 8; ++r) {
                    float y = Yb[r];
                    re[r] = fmaf(y, wcf, re[r]);
                    im[r] = fmaf(y, wsf, im[r]);
                }
                double nwc = fma(wc, c1, -ws * s1);
                double nws = fma(wc, s1,  ws * c1);
                wc = nwc; ws = nws;
            }
        } else {
            // odd k: Y = d02 + i*t*d13, t=+1 (q=1) / -1 (q=3); 4 FMA/r, 4 b128/iter
            const float tq = (k & 2) ? -1.f : 1.f;
            for (int j = 0; j < 25; ++j) {
                const float* Ar = d02S + (b0 + j) * 8;
                const float* Ai = d13S + (b0 + j) * 8;
                float wcf = (float)wc, wsf = (float)ws;
                float u = tq * wcf, v = tq * wsf;
#pragma unroll
                for (int r = 0; r < 8; ++r) {
                    float ar = Ar[r], ai = Ai[r];
                    re[r] = fmaf(ar, wcf, re[r]);
                    re[r] = fmaf(ai, -v,  re[r]);
                    im[r] = fmaf(ar, wsf, im[r]);
                    im[r] = fmaf(ai, u,   im[r]);
                }
                double nwc = fma(wc, c1, -ws * s1);
                double nws = fma(wc, s1,  ws * c1);
                wc = nwc; ws = nws;
            }
        }
        if (bgrp == 1) {
#pragma unroll
            for (int r = 0; r < 8; ++r) { reS[k * 8 + r] = re[r]; imS[k * 8 + r] = im[r]; }
        }
    }
    __syncthreads();
    // combine b-groups (each k owned by exactly one bgrp0 thread)
    if (bgrp == 0 && act) {
#pragma unroll
        for (int r = 0; r < 8; ++r) {
            re[r] += reS[k * 8 + r]; im[r] += imS[k * 8 + r];
            reS[k * 8 + r] = re[r];  imS[k * 8 + r] = im[r];
        }
    }
    __syncthreads();
    // amp/phase on ALL 256 threads, f32 fast path; rare exact-f64 fallback for small bins
    // (xsT still alive -> fallback recomputes the bin from the exact f32 inputs)
    for (int e = tid; e < FREQ * 8; e += 256) {
        float c = reS[e], s = imS[e];
        float a2 = fmaf(c, c, s * s);
        float ampv, phv;
        if (a2 >= 0.04f) {
            ampv = sqrtf(a2);
            phv  = atan2f(s, c);
        } else {
            const int kk = e >> 3, rr = e & 7;
            double sg = (kk & 1) ? -1.0 : 1.0;
            double reD = (double)xsT[rr] + sg * (double)xsT[100 * 9 + rr];
            double imD = 0.0;
            double cc1, ss1;
            cis_exact(kk, cc1, ss1);
            double twc = cc1, tws = ss1;             // w at n=1
            for (int n = 1; n < 100; ++n) {
                double a = (double)xsT[n * 9 + rr];
                double b = (double)xsT[(IN_DIM - n) * 9 + rr];
                reD = fma(a + b, twc, reD);
                imD = fma(a - b, tws, imD);
                double nwc = fma(twc, cc1, -tws * ss1);
                double nws = fma(twc, ss1,  tws * cc1);
                twc = nwc; tws = nws;
            }
            ampv = (float)sqrt(reD * reD + imD * imD);
            phv  = (float)atan2(imD, reD);
        }
        reS[e] = ampv; imS[e] = phv;
    }
    __syncthreads();

    // projection in f32: d = tid&63; which = amp/phase; grp splits kk range 51/50
    const int d = tid & 63, which = (tid >> 6) & 1, grp = tid >> 7;
    const float* proj = which ? projP : projA;
    const float* srcF = which ? imS : reS;          // [k][8], k-major
    float acc[8];
#pragma unroll
    for (int r = 0; r < 8; ++r) acc[r] = 0.f;
    const int kkA = grp ? 51 : 0;
    const int kkB = grp ? FREQ : 51;
    for (int kk = kkA; kk < kkB; ++kk) {
        float p = proj[kk * VQD + d];
#pragma unroll
        for (int r = 0; r < 8; ++r) acc[r] = fmaf(srcF[kk * 8 + r], p, acc[r]);
    }
    if (grp) {
#pragma unroll
        for (int r = 0; r < 8; ++r) accS[(tid & 127) * 8 + r] = acc[r];
    }
    __syncthreads();
    if (grp == 0) {
#pragma unroll
        for (int r = 0; r < 8; ++r) acc[r] += accS[tid * 8 + r];
#pragma unroll
        for (int r = 0; r < 8; ++r) {
            size_t rowi = (size_t)which * ROWS + r0 + r;
            float vf = acc[r];
            unsigned short hb = f2bf(vf);
            unsigned short lb = f2bf(vf - bf2f(hb));
            ftH[rowi * VQD + d] = hb;
            ftL[rowi * VQD + d] = lb;
            featF[rowi * VQD + d] = vf;
        }
    }
}

// ---------------- 2. bf16x3 MFMA sim + top-2, DMA double-buffered prefetch ----------------
// r23: (a) z-SPLIT: launched twice with zofs in {0,2}, grid (152,2,2) — halves the
// per-dispatch duration to ~78 us so dft_cb can surface in rocprof's top-5 table
// (attribution probe; costs one dispatch). (b) UPD 8 -> 7 VALU ops, bitwise-exact:
// b2v = v_med3_f32(v, b1v, b2v) — the median of {new, best, second} IS the new
// second — and b1v = fmaxf(v, b1v); compares use pre-update values; index cndmasks
// unchanged. argmax is issue-saturated (VALU 64% + MFMA 34%), so -12% VALU inst
// should convert ~1:1.
#define MFMA(a, b, c) __builtin_amdgcn_mfma_f32_16x16x32_bf16(a, b, c, 0, 0, 0)
#define UPD(val, s) do { float _v = (val); \
    bool _c1 = _v > b1v[s]; bool _c2 = _v > b2v[s]; \
    b2v[s] = __builtin_amdgcn_fmed3f(_v, b1v[s], b2v[s]); \
    b1v[s] = fmaxf(_v, b1v[s]); \
    b2i[s] = _c1 ? b1i[s] : (_c2 ? idx : b2i[s]); \
    b1i[s] = _c1 ? idx : b1i[s]; } while (0)

__global__ __launch_bounds__(256, 3) void argmax_kernel(
    const unsigned short* __restrict__ ftH, const unsigned short* __restrict__ ftL,
    const unsigned short* __restrict__ cbH, const unsigned short* __restrict__ cbL,
    int* __restrict__ pi1, int* __restrict__ pi2, int zofs)
{
    __shared__ __align__(16) char lds[33792];
    const int tid = threadIdx.x;
    const int f = blockIdx.y, z = blockIdx.z + zofs;
    const int r0 = blockIdx.x * 128;
    const int w = tid >> 6, lane = tid & 63;
    const int q = lane >> 4, cl = lane & 15;

    const unsigned short* ftHb = ftH + (size_t)f * ROWS * VQD;
    const unsigned short* ftLb = ftL + (size_t)f * ROWS * VQD;
    const unsigned short* cbHb = cbH + (size_t)f * NEMB * VQD;
    const unsigned short* cbLb = cbL + (size_t)f * NEMB * VQD;

    short8 aH00, aH01, aH10, aH11, aL00, aL01, aL10, aL11;
    {
        const size_t baseA = (size_t)(r0 + w * 32 + cl) * VQD + q * 8;
        const size_t baseB = baseA + (size_t)16 * VQD;
        aH00 = *(const short8*)(ftHb + baseA);
        aH01 = *(const short8*)(ftHb + baseA + 32);
        aH10 = *(const short8*)(ftHb + baseB);
        aH11 = *(const short8*)(ftHb + baseB + 32);
        aL00 = *(const short8*)(ftLb + baseA);
        aL01 = *(const short8*)(ftLb + baseA + 32);
        aL10 = *(const short8*)(ftLb + baseB);
        aL11 = *(const short8*)(ftLb + baseB + 32);
    }

    float b1v[8], b2v[8]; int b1i[8], b2i[8];
#pragma unroll
    for (int s = 0; s < 8; ++s) { b1v[s] = -INFINITY; b2v[s] = -INFINITY; b1i[s] = 0; b2i[s] = 0; }

    const int cBase = tid >> 3;
    const int jel   = (((tid & 7) ^ (cBase & 7)) << 3);
    const unsigned short* gH = cbHb + (size_t)(z * 2048 + cBase) * VQD + jel;
    const unsigned short* gL = cbLb + (size_t)(z * 2048 + cBase) * VQD + jel;

    const int p0 = ((q ^ (cl & 7)) << 4);
    const int p1 = p0 ^ 64;

#pragma unroll
    for (int r = 0; r < 2; ++r) {
        const size_t gofs = (size_t)(32 * r) * VQD;
        GLOAD_LDS(gH + gofs, lds + w * 1024 + r * 4096);
        GLOAD_LDS(gL + gofs, lds + 8192 + w * 1024 + r * 4096);
    }

    for (int it = 0; it < 32; ++it) {
        __syncthreads();
        if (it < 31) {
            char* nbuf = lds + ((it + 1) & 1) * 16384;
            const size_t gbase = (size_t)((it + 1) * 64) * VQD;
#pragma unroll
            for (int r = 0; r < 2; ++r) {
                const size_t gofs = gbase + (size_t)(32 * r) * VQD;
                GLOAD_LDS(gH + gofs, nbuf + w * 1024 + r * 4096);
                GLOAD_LDS(gL + gofs, nbuf + 8192 + w * 1024 + r * 4096);
            }
        }

        const char* buf = lds + (it & 1) * 16384;
        const int cbase = z * 2048 + it * 64;
#pragma unroll
        for (int nt = 0; nt < 4; ++nt) {
            const char* row = buf + (nt * 16 + cl) * 128;
            short8 bH0 = *(const short8*)(row + p0);
            short8 bH1 = *(const short8*)(row + p1);
            short8 bL0 = *(const short8*)(row + 8192 + p0);
            short8 bL1 = *(const short8*)(row + 8192 + p1);

            floatx4 acc0 = {0.f, 0.f, 0.f, 0.f};
            floatx4 acc1 = {0.f, 0.f, 0.f, 0.f};
            acc0 = MFMA(aH00, bH0, acc0);  acc1 = MFMA(aH10, bH0, acc1);
            acc0 = MFMA(aH01, bH1, acc0);  acc1 = MFMA(aH11, bH1, acc1);
            acc0 = MFMA(aH00, bL0, acc0);  acc1 = MFMA(aH10, bL0, acc1);
            acc0 = MFMA(aH01, bL1, acc0);  acc1 = MFMA(aH11, bL1, acc1);
            acc0 = MFMA(aL00, bH0, acc0);  acc1 = MFMA(aL10, bH0, acc1);
            acc0 = MFMA(aL01, bH1, acc0);  acc1 = MFMA(aL11, bH1, acc1);

            const int idx = cbase + nt * 16 + cl;
#pragma unroll
            for (int i = 0; i < 4; ++i) { UPD(acc0[i], i); UPD(acc1[i], 4 + i); }
        }
    }

    __syncthreads();
    float* redv = (float*)lds;           // [128][33]
    int*   redi = (int*)(lds + 128 * 33 * 4);
#pragma unroll
    for (int s = 0; s < 8; ++s) {
        int rowl = w * 32 + ((s & 4) << 2) + q * 4 + (s & 3);   // +16 when s>=4
        int base = rowl * 33 + cl * 2;
        redv[base]     = b1v[s]; redi[base]     = b1i[s];
        redv[base + 1] = b2v[s]; redi[base + 1] = b2i[s];
    }
    __syncthreads();
    if (tid < 128) {
        float v1 = -INFINITY, v2 = -INFINITY; int i1 = 0x7fffffff, i2 = 0x7fffffff;
        for (int e = 0; e < 32; ++e) {
            float v = redv[tid * 33 + e]; int id = redi[tid * 33 + e];
            if (v > v1 || (v == v1 && id < i1)) { v2 = v1; i2 = i1; v1 = v; i1 = id; }
            else if (v > v2 || (v == v2 && id < i2)) { v2 = v; i2 = id; }
        }
        size_t p = ((size_t)(f * 4 + z)) * ROWS + r0 + tid;
        pi1[p] = i1; pi2[p] = i2;
    }
}

// ---------------- 3. f64 rescore of the 8 candidates/row (r19 structure; f32 feat input,
// upcast exactly -> bitwise-identical rescoring) ----------------
__global__ __launch_bounds__(256) void rescore_kernel(
    const float* __restrict__ featF, const double* __restrict__ invnD,
    const float* __restrict__ cbA, const float* __restrict__ cbP,
    const int* __restrict__ pi1, const int* __restrict__ pi2,
    int* __restrict__ out)
{
    const int tid = threadIdx.x;
    const int lane = tid & 63, wave = tid >> 6;
    const int task = blockIdx.x * 4 + wave;           // 0 .. 2*ROWS-1
    const int f = task / ROWS;
    const int row = task - f * ROWS;
    const float* cb = f ? cbP : cbA;

    const int c  = lane >> 3;        // candidate 0..7
    const int dp = (lane & 7) * 8;   // d-slice base

    const int zz = c >> 1;
    const size_t p = ((size_t)(f * 4 + zz)) * ROWS + row;
    const int idx = (c & 1) ? pi2[p] : pi1[p];

    const float* fr = featF + ((size_t)f * ROWS + row) * VQD + dp;
    const float* cr = cb + (size_t)idx * VQD + dp;
    double t = 0.0;
#pragma unroll
    for (int j = 0; j < 8; ++j) t = fma((double)fr[j], (double)cr[j], t);
    t += __shfl_xor(t, 1, 64);
    t += __shfl_xor(t, 2, 64);
    t += __shfl_xor(t, 4, 64);
    double bv = t * invnD[(size_t)f * NEMB + idx];
    int    bi = idx;
#pragma unroll
    for (int m = 8; m <= 32; m <<= 1) {
        double ov = __shfl_xor(bv, m, 64);
        int    oi = __shfl_xor(bi, m, 64);
        if (ov > bv || (ov == bv && oi < bi)) { bv = ov; bi = oi; }
    }
    if (lane == 0) out[task] = bi;
}

// ---------------- launch ----------------
extern "C" void kernel_launch(void* const* d_in, const int* in_sizes, int n_in,
                              void* d_out, int out_size, void* d_ws, size_t ws_size,
                              hipStream_t stream)
{
    const float* x     = (const float*)d_in[0];
    const float* projA = (const float*)d_in[1];
    const float* projP = (const float*)d_in[2];
    const float* cbA   = (const float*)d_in[3];
    const float* cbP   = (const float*)d_in[4];

    char* ws = (char*)d_ws;
    unsigned short* ftH   = (unsigned short*)(ws + OFF_FTH);
    unsigned short* ftL   = (unsigned short*)(ws + OFF_FTL);
    unsigned short* cbHp  = (unsigned short*)(ws + OFF_CBH);
    unsigned short* cbLp  = (unsigned short*)(ws + OFF_CBL);
    float*          featF = (float*)(ws + OFF_FD);
    double*         invnD = (double*)(ws + OFF_INV);
    int*            pi1   = (int*)(ws + OFF_PI1);
    int*            pi2   = (int*)(ws + OFF_PI2);

    dft_cb_kernel<<<DFT_BLOCKS + 256, 256, 0, stream>>>(
        x, projA, projP, cbA, cbP, ftH, ftL, featF, cbHp, cbLp, invnD);
    argmax_kernel<<<dim3(ROWS / 128, 2, 2), 256, 0, stream>>>(ftH, ftL, cbHp, cbLp, pi1, pi2, 0);
    argmax_kernel<<<dim3(ROWS / 128, 2, 2), 256, 0, stream>>>(ftH, ftL, cbHp, cbLp, pi1, pi2, 2);
    rescore_kernel<<<(2 * ROWS) / 4, 256, 0, stream>>>(featF, invnD, cbA, cbP, pi1, pi2, (int*)d_out);
}

// Round 7
// 306.920 us; speedup vs baseline: 1.0985x; 1.0985x over previous
//
#include <hip/hip_runtime.h>
#include <math.h>

// Problem constants
constexpr int ROWS  = 19456;   // B*C*N = 16*19*64
constexpr int IN_DIM = 200;
constexpr int FREQ  = 101;     // rfft bins
constexpr int VQD   = 64;
constexpr int NEMB  = 8192;
constexpr int DFT_BLOCKS = ROWS / 8;   // 2432

typedef __attribute__((ext_vector_type(8))) short short8;   // 8 bf16 = 4 VGPRs
typedef __attribute__((ext_vector_type(4))) float floatx4;

__device__ __forceinline__ unsigned short f2bf(float v) {   // RTN-even fp32->bf16
    unsigned int u = __builtin_bit_cast(unsigned int, v);
    unsigned int r = u + 0x7fffu + ((u >> 16) & 1u);
    return (unsigned short)(r >> 16);
}
__device__ __forceinline__ float bf2f(unsigned short b) {
    unsigned int u = ((unsigned int)b) << 16;
    return __builtin_bit_cast(float, u);
}

// cis(-2*pi*r/200) with exact quarter points (bitwise-identical to the r1-validated table)
__device__ __forceinline__ void cis_exact(int r, double& c, double& s) {
    if (r == 0)        { c =  1.0; s =  0.0; }
    else if (r == 50)  { c =  0.0; s = -1.0; }
    else if (r == 100) { c = -1.0; s =  0.0; }
    else if (r == 150) { c =  0.0; s =  1.0; }
    else {
        double ang = -6.283185307179586476925286766559 * (double)r / (double)IN_DIM;
        c = cos(ang); s = sin(ang);
    }
}

// async global->LDS DMA, 16 B per lane; LDS dest = wave-uniform base + lane*16
#define GLOAD_LDS(gp, lp) __builtin_amdgcn_global_load_lds( \
    (const __attribute__((address_space(1))) unsigned int*)(gp), \
    (__attribute__((address_space(3))) unsigned int*)(lp), 16, 0, 0)

// ---------------- workspace layout ----------------
constexpr size_t align256(size_t x) { return (x + 255) & ~(size_t)255; }
constexpr size_t SZ_FB    = (size_t)2 * ROWS * VQD * sizeof(unsigned short); // bf16 feats [2][ROWS][64]
constexpr size_t OFF_FTH  = 0;
constexpr size_t OFF_FTL  = align256(OFF_FTH + SZ_FB);
constexpr size_t SZ_CBB   = (size_t)2 * NEMB * VQD * sizeof(unsigned short); // bf16 codes [2][8192][64]
constexpr size_t OFF_CBH  = align256(OFF_FTL + SZ_FB);
constexpr size_t OFF_CBL  = align256(OFF_CBH + SZ_CBB);
constexpr size_t SZ_FD    = (size_t)2 * ROWS * VQD * sizeof(double);         // feat slot (f32, oversized ok)
constexpr size_t OFF_FD   = align256(OFF_CBL + SZ_CBB);
constexpr size_t SZ_INV   = (size_t)2 * NEMB * sizeof(double);               // f64 1/||cb||
constexpr size_t OFF_INV  = align256(OFF_FD + SZ_FD);
constexpr size_t SZ_PI    = (size_t)2 * 4 * ROWS * sizeof(int);              // top-2 per 2048-chunk
constexpr size_t OFF_PI1  = align256(OFF_INV + SZ_INV);
constexpr size_t OFF_PI2  = align256(OFF_PI1 + SZ_PI);

// ---------------- 1. fused DFT/proj (blocks < 2432) + cb_prep (blocks >= 2432) ----------------
// r24: r4 radix-4 body, plain launch_bounds, f32 featF. (r6's z-split probe showed
// argmax needs the full 1216-block grid — occupancy 30.9->20.5, MfmaUtil 34->21 at
// half grid — and bounded dft_cb < ~118 us without surfacing it.)
// LDS plan (20064 B):
//   [    0,  7200) xsT  f32 [n=200][r] stride 9
//   [ 7200,  8800) e0   f32 [50][8]   x0+x2+x1+x3   (q=0)
//   [ 8800, 10400) e2   f32 [50][8]   x0+x2-x1-x3   (q=2)
//   [10400, 12000) d02  f32 [50][8]   x0-x2         (q=1,3 re)
//   [12000, 13600) d13  f32 [50][8]   x3-x1         (q=1,3 im)
//   [13600, 16832) reS  f32 [k][8]: cisT (f64[101][2]) -> bgrp1 re -> final re -> amp
//   [16832, 20064) imS  f32 [k][8]: bgrp1 im -> final im -> phase
//   projection phase: accS f32 [128][8] aliases e0 base (e-arrays dead after loop)
__global__ __launch_bounds__(256) void dft_cb_kernel(
    const float* __restrict__ x, const float* __restrict__ projA, const float* __restrict__ projP,
    const float* __restrict__ cbA, const float* __restrict__ cbP,
    unsigned short* __restrict__ ftH, unsigned short* __restrict__ ftL, float* __restrict__ featF,
    unsigned short* __restrict__ cbH, unsigned short* __restrict__ cbL, double* __restrict__ invnD)
{
    __shared__ __align__(16) char smem[20064];
    const int tid = threadIdx.x;

    if (blockIdx.x >= DFT_BLOCKS) {
        // ---- cb_prep body (validated rounds 5-16, unchanged) ----
        float* tile = (float*)smem;            // 64*65*4 = 16640 B
        float* inv  = (float*)(smem + 16640);  // 256 B
        const int bid2 = blockIdx.x - DFT_BLOCKS;
        const int which = bid2 >> 7;
        const int m0 = (bid2 & 127) * 64;
        const float* cb = which ? cbP : cbA;
        for (int e = tid; e < 4096; e += 256) {
            int c = e >> 6, d = e & 63;
            tile[c * 65 + d] = cb[(size_t)(m0 + c) * VQD + d];
        }
        __syncthreads();
        if (tid < 64) {
            double s = 0.0;
            for (int d2 = 0; d2 < 64; ++d2) { double v = (double)tile[tid * 65 + d2]; s += v * v; }
            inv[tid] = (float)(1.0 / sqrt(s));
            invnD[(size_t)which * NEMB + m0 + tid] = 1.0 / sqrt(s);
        }
        __syncthreads();
        for (int e = tid; e < 4096; e += 256) {
            int c = e >> 6, d = e & 63;
            float v = tile[c * 65 + d] * inv[c];
            unsigned short hb = f2bf(v);
            unsigned short lb = f2bf(v - bf2f(hb));
            size_t o = ((size_t)which * NEMB + m0 + c) * VQD + d;
            cbH[o] = hb; cbL[o] = lb;
        }
        return;
    }

    float*  xsT  = (float*)smem;                 // [n][r] stride 9
    float*  e0S  = (float*)(smem + 7200);        // [50][8]
    float*  e2S  = (float*)(smem + 8800);
    float*  d02S = (float*)(smem + 10400);
    float*  d13S = (float*)(smem + 12000);
    float*  reS  = (float*)(smem + 13600);       // [k][8]
    float*  imS  = (float*)(smem + 16832);
    double* cisT = (double*)(smem + 13600);      // f64[101][2] = 1616 B, aliases reS (dead)
    float*  accS = (float*)(smem + 7200);        // proj partials, after e-arrays die
    const int r0 = blockIdx.x * 8;

    for (int e = tid; e < 8 * IN_DIM; e += 256) {
        int r = e / IN_DIM, n = e - r * IN_DIM;
        xsT[n * 9 + r] = x[(size_t)(r0 + r) * IN_DIM + n];
    }
    __syncthreads();

    // radix-4 prep: 4-point DFT over a (n = 50a+b), adds only, f32
    for (int e = tid; e < 50 * 8; e += 256) {
        int b = e >> 3, r = e & 7;
        float x0 = xsT[b * 9 + r];
        float x1 = xsT[(50 + b) * 9 + r];
        float x2 = xsT[(100 + b) * 9 + r];
        float x3 = xsT[(150 + b) * 9 + r];
        float s02 = x0 + x2, dd02 = x0 - x2;
        float s13 = x1 + x3, dd13 = x3 - x1;
        e0S[e]  = s02 + s13;
        e2S[e]  = s02 - s13;
        d02S[e] = dd02;
        d13S[e] = dd13;
    }
    // cis table: one f64 sincos per k, computed once per block (2 wave-calls)
    if (tid < FREQ) {
        double c, s;
        cis_exact(tid, c, s);
        cisT[tid * 2]     = c;
        cisT[tid * 2 + 1] = s;
    }
    __syncthreads();

    // q-homogeneous wave mapping: parity = wave&1 selects k parity; bgrp = wave>>1
    const int lane = tid & 63, wv = tid >> 6;
    const int parity = wv & 1, bgrp = wv >> 1;
    const int k = 2 * lane + parity;
    const bool act = (k < FREQ);                 // even wave: 51 lanes, odd: 50

    double c1 = 1.0, s1 = 0.0, wc = 1.0, ws = 0.0;
    if (act) {
        c1 = cisT[k * 2]; s1 = cisT[k * 2 + 1];
        if (bgrp) {
            // start twiddle W^{25k} = e^{-i pi (k&7)/4}: exact eighth points
            const double RH = 0.70710678118654752440;
            switch (k & 7) {
                case 0:  wc =  1.0; ws =  0.0; break;
                case 1:  wc =  RH;  ws = -RH;  break;
                case 2:  wc =  0.0; ws = -1.0; break;
                case 3:  wc = -RH;  ws = -RH;  break;
                case 4:  wc = -1.0; ws =  0.0; break;
                case 5:  wc = -RH;  ws =  RH;  break;
                case 6:  wc =  0.0; ws =  1.0; break;
                default: wc =  RH;  ws =  RH;  break;
            }
        }
    }
    __syncthreads();   // seals cisT before bgrp1's reS stores (table now dead)

    float re[8], im[8];
    if (act) {
#pragma unroll
        for (int r = 0; r < 8; ++r) { re[r] = 0.f; im[r] = 0.f; }
        const int b0 = bgrp * 25;
        if (parity == 0) {
            // even k: Y real = e0 (q=0) or e2 (q=2); 2 FMA/r, 2 b128/iter
            const float* Y = (k & 2) ? e2S : e0S;
            for (int j = 0; j < 25; ++j) {
                const float* Yb = Y + (b0 + j) * 8;
                float wcf = (float)wc, wsf = (float)ws;
#pragma unroll
                for (int r = 0; r < 8; ++r) {
                    float y = Yb[r];
                    re[r] = fmaf(y, wcf, re[r]);
                    im[r] = fmaf(y, wsf, im[r]);
                }
                double nwc = fma(wc, c1, -ws * s1);
                double nws = fma(wc, s1,  ws * c1);
                wc = nwc; ws = nws;
            }
        } else {
            // odd k: Y = d02 + i*t*d13, t=+1 (q=1) / -1 (q=3); 4 FMA/r, 4 b128/iter
            const float tq = (k & 2) ? -1.f : 1.f;
            for (int j = 0; j < 25; ++j) {
                const float* Ar = d02S + (b0 + j) * 8;
                const float* Ai = d13S + (b0 + j) * 8;
                float wcf = (float)wc, wsf = (float)ws;
                float u = tq * wcf, v = tq * wsf;
#pragma unroll
                for (int r = 0; r < 8; ++r) {
                    float ar = Ar[r], ai = Ai[r];
                    re[r] = fmaf(ar, wcf, re[r]);
                    re[r] = fmaf(ai, -v,  re[r]);
                    im[r] = fmaf(ar, wsf, im[r]);
                    im[r] = fmaf(ai, u,   im[r]);
                }
                double nwc = fma(wc, c1, -ws * s1);
                double nws = fma(wc, s1,  ws * c1);
                wc = nwc; ws = nws;
            }
        }
        if (bgrp == 1) {
#pragma unroll
            for (int r = 0; r < 8; ++r) { reS[k * 8 + r] = re[r]; imS[k * 8 + r] = im[r]; }
        }
    }
    __syncthreads();
    // combine b-groups (each k owned by exactly one bgrp0 thread)
    if (bgrp == 0 && act) {
#pragma unroll
        for (int r = 0; r < 8; ++r) {
            re[r] += reS[k * 8 + r]; im[r] += imS[k * 8 + r];
            reS[k * 8 + r] = re[r];  imS[k * 8 + r] = im[r];
        }
    }
    __syncthreads();
    // amp/phase on ALL 256 threads, f32 fast path; rare exact-f64 fallback for small bins
    // (xsT still alive -> fallback recomputes the bin from the exact f32 inputs)
    for (int e = tid; e < FREQ * 8; e += 256) {
        float c = reS[e], s = imS[e];
        float a2 = fmaf(c, c, s * s);
        float ampv, phv;
        if (a2 >= 0.04f) {
            ampv = sqrtf(a2);
            phv  = atan2f(s, c);
        } else {
            const int kk = e >> 3, rr = e & 7;
            double sg = (kk & 1) ? -1.0 : 1.0;
            double reD = (double)xsT[rr] + sg * (double)xsT[100 * 9 + rr];
            double imD = 0.0;
            double cc1, ss1;
            cis_exact(kk, cc1, ss1);
            double twc = cc1, tws = ss1;             // w at n=1
            for (int n = 1; n < 100; ++n) {
                double a = (double)xsT[n * 9 + rr];
                double b = (double)xsT[(IN_DIM - n) * 9 + rr];
                reD = fma(a + b, twc, reD);
                imD = fma(a - b, tws, imD);
                double nwc = fma(twc, cc1, -tws * ss1);
                double nws = fma(twc, ss1,  tws * cc1);
                twc = nwc; tws = nws;
            }
            ampv = (float)sqrt(reD * reD + imD * imD);
            phv  = (float)atan2(imD, reD);
        }
        reS[e] = ampv; imS[e] = phv;
    }
    __syncthreads();

    // projection in f32: d = tid&63; which = amp/phase; grp splits kk range 51/50
    const int d = tid & 63, which = (tid >> 6) & 1, grp = tid >> 7;
    const float* proj = which ? projP : projA;
    const float* srcF = which ? imS : reS;          // [k][8], k-major
    float acc[8];
#pragma unroll
    for (int r = 0; r < 8; ++r) acc[r] = 0.f;
    const int kkA = grp ? 51 : 0;
    const int kkB = grp ? FREQ : 51;
    for (int kk = kkA; kk < kkB; ++kk) {
        float p = proj[kk * VQD + d];
#pragma unroll
        for (int r = 0; r < 8; ++r) acc[r] = fmaf(srcF[kk * 8 + r], p, acc[r]);
    }
    if (grp) {
#pragma unroll
        for (int r = 0; r < 8; ++r) accS[(tid & 127) * 8 + r] = acc[r];
    }
    __syncthreads();
    if (grp == 0) {
#pragma unroll
        for (int r = 0; r < 8; ++r) acc[r] += accS[tid * 8 + r];
#pragma unroll
        for (int r = 0; r < 8; ++r) {
            size_t rowi = (size_t)which * ROWS + r0 + r;
            float vf = acc[r];
            unsigned short hb = f2bf(vf);
            unsigned short lb = f2bf(vf - bf2f(hb));
            ftH[rowi * VQD + d] = hb;
            ftL[rowi * VQD + d] = lb;
            featF[rowi * VQD + d] = vf;
        }
    }
}

// ---------------- 2. bf16x3 MFMA sim + top-2, DMA double-buffered prefetch ----------------
// r24: single full-grid launch restored (r6 z-split cost +64 us via occupancy loss).
// UPD kept at the 7-op bitwise-exact form: b2v = med3(v, b1v, b2v) — the median of
// {new, best, second} IS the new second — and b1v = fmax(v, b1v); compares use
// pre-update values; index cndmasks unchanged.
#define MFMA(a, b, c) __builtin_amdgcn_mfma_f32_16x16x32_bf16(a, b, c, 0, 0, 0)
#define UPD(val, s) do { float _v = (val); \
    bool _c1 = _v > b1v[s]; bool _c2 = _v > b2v[s]; \
    b2v[s] = __builtin_amdgcn_fmed3f(_v, b1v[s], b2v[s]); \
    b1v[s] = fmaxf(_v, b1v[s]); \
    b2i[s] = _c1 ? b1i[s] : (_c2 ? idx : b2i[s]); \
    b1i[s] = _c1 ? idx : b1i[s]; } while (0)

__global__ __launch_bounds__(256, 3) void argmax_kernel(
    const unsigned short* __restrict__ ftH, const unsigned short* __restrict__ ftL,
    const unsigned short* __restrict__ cbH, const unsigned short* __restrict__ cbL,
    int* __restrict__ pi1, int* __restrict__ pi2)
{
    __shared__ __align__(16) char lds[33792];
    const int tid = threadIdx.x;
    const int f = blockIdx.y, z = blockIdx.z;
    const int r0 = blockIdx.x * 128;
    const int w = tid >> 6, lane = tid & 63;
    const int q = lane >> 4, cl = lane & 15;

    const unsigned short* ftHb = ftH + (size_t)f * ROWS * VQD;
    const unsigned short* ftLb = ftL + (size_t)f * ROWS * VQD;
    const unsigned short* cbHb = cbH + (size_t)f * NEMB * VQD;
    const unsigned short* cbLb = cbL + (size_t)f * NEMB * VQD;

    short8 aH00, aH01, aH10, aH11, aL00, aL01, aL10, aL11;
    {
        const size_t baseA = (size_t)(r0 + w * 32 + cl) * VQD + q * 8;
        const size_t baseB = baseA + (size_t)16 * VQD;
        aH00 = *(const short8*)(ftHb + baseA);
        aH01 = *(const short8*)(ftHb + baseA + 32);
        aH10 = *(const short8*)(ftHb + baseB);
        aH11 = *(const short8*)(ftHb + baseB + 32);
        aL00 = *(const short8*)(ftLb + baseA);
        aL01 = *(const short8*)(ftLb + baseA + 32);
        aL10 = *(const short8*)(ftLb + baseB);
        aL11 = *(const short8*)(ftLb + baseB + 32);
    }

    float b1v[8], b2v[8]; int b1i[8], b2i[8];
#pragma unroll
    for (int s = 0; s < 8; ++s) { b1v[s] = -INFINITY; b2v[s] = -INFINITY; b1i[s] = 0; b2i[s] = 0; }

    const int cBase = tid >> 3;
    const int jel   = (((tid & 7) ^ (cBase & 7)) << 3);
    const unsigned short* gH = cbHb + (size_t)(z * 2048 + cBase) * VQD + jel;
    const unsigned short* gL = cbLb + (size_t)(z * 2048 + cBase) * VQD + jel;

    const int p0 = ((q ^ (cl & 7)) << 4);
    const int p1 = p0 ^ 64;

#pragma unroll
    for (int r = 0; r < 2; ++r) {
        const size_t gofs = (size_t)(32 * r) * VQD;
        GLOAD_LDS(gH + gofs, lds + w * 1024 + r * 4096);
        GLOAD_LDS(gL + gofs, lds + 8192 + w * 1024 + r * 4096);
    }

    for (int it = 0; it < 32; ++it) {
        __syncthreads();
        if (it < 31) {
            char* nbuf = lds + ((it + 1) & 1) * 16384;
            const size_t gbase = (size_t)((it + 1) * 64) * VQD;
#pragma unroll
            for (int r = 0; r < 2; ++r) {
                const size_t gofs = gbase + (size_t)(32 * r) * VQD;
                GLOAD_LDS(gH + gofs, nbuf + w * 1024 + r * 4096);
                GLOAD_LDS(gL + gofs, nbuf + 8192 + w * 1024 + r * 4096);
            }
        }

        const char* buf = lds + (it & 1) * 16384;
        const int cbase = z * 2048 + it * 64;
#pragma unroll
        for (int nt = 0; nt < 4; ++nt) {
            const char* row = buf + (nt * 16 + cl) * 128;
            short8 bH0 = *(const short8*)(row + p0);
            short8 bH1 = *(const short8*)(row + p1);
            short8 bL0 = *(const short8*)(row + 8192 + p0);
            short8 bL1 = *(const short8*)(row + 8192 + p1);

            floatx4 acc0 = {0.f, 0.f, 0.f, 0.f};
            floatx4 acc1 = {0.f, 0.f, 0.f, 0.f};
            acc0 = MFMA(aH00, bH0, acc0);  acc1 = MFMA(aH10, bH0, acc1);
            acc0 = MFMA(aH01, bH1, acc0);  acc1 = MFMA(aH11, bH1, acc1);
            acc0 = MFMA(aH00, bL0, acc0);  acc1 = MFMA(aH10, bL0, acc1);
            acc0 = MFMA(aH01, bL1, acc0);  acc1 = MFMA(aH11, bL1, acc1);
            acc0 = MFMA(aL00, bH0, acc0);  acc1 = MFMA(aL10, bH0, acc1);
            acc0 = MFMA(aL01, bH1, acc0);  acc1 = MFMA(aL11, bH1, acc1);

            const int idx = cbase + nt * 16 + cl;
#pragma unroll
            for (int i = 0; i < 4; ++i) { UPD(acc0[i], i); UPD(acc1[i], 4 + i); }
        }
    }

    __syncthreads();
    float* redv = (float*)lds;           // [128][33]
    int*   redi = (int*)(lds + 128 * 33 * 4);
#pragma unroll
    for (int s = 0; s < 8; ++s) {
        int rowl = w * 32 + ((s & 4) << 2) + q * 4 + (s & 3);   // +16 when s>=4
        int base = rowl * 33 + cl * 2;
        redv[base]     = b1v[s]; redi[base]     = b1i[s];
        redv[base + 1] = b2v[s]; redi[base + 1] = b2i[s];
    }
    __syncthreads();
    if (tid < 128) {
        float v1 = -INFINITY, v2 = -INFINITY; int i1 = 0x7fffffff, i2 = 0x7fffffff;
        for (int e = 0; e < 32; ++e) {
            float v = redv[tid * 33 + e]; int id = redi[tid * 33 + e];
            if (v > v1 || (v == v1 && id < i1)) { v2 = v1; i2 = i1; v1 = v; i1 = id; }
            else if (v > v2 || (v == v2 && id < i2)) { v2 = v; i2 = id; }
        }
        size_t p = ((size_t)(f * 4 + z)) * ROWS + r0 + tid;
        pi1[p] = i1; pi2[p] = i2;
    }
}

// ---------------- 3. f64 rescore of the 8 candidates/row (r19 structure; f32 feat input,
// upcast exactly -> bitwise-identical rescoring) ----------------
__global__ __launch_bounds__(256) void rescore_kernel(
    const float* __restrict__ featF, const double* __restrict__ invnD,
    const float* __restrict__ cbA, const float* __restrict__ cbP,
    const int* __restrict__ pi1, const int* __restrict__ pi2,
    int* __restrict__ out)
{
    const int tid = threadIdx.x;
    const int lane = tid & 63, wave = tid >> 6;
    const int task = blockIdx.x * 4 + wave;           // 0 .. 2*ROWS-1
    const int f = task / ROWS;
    const int row = task - f * ROWS;
    const float* cb = f ? cbP : cbA;

    const int c  = lane >> 3;        // candidate 0..7
    const int dp = (lane & 7) * 8;   // d-slice base

    const int zz = c >> 1;
    const size_t p = ((size_t)(f * 4 + zz)) * ROWS + row;
    const int idx = (c & 1) ? pi2[p] : pi1[p];

    const float* fr = featF + ((size_t)f * ROWS + row) * VQD + dp;
    const float* cr = cb + (size_t)idx * VQD + dp;
    double t = 0.0;
#pragma unroll
    for (int j = 0; j < 8; ++j) t = fma((double)fr[j], (double)cr[j], t);
    t += __shfl_xor(t, 1, 64);
    t += __shfl_xor(t, 2, 64);
    t += __shfl_xor(t, 4, 64);
    double bv = t * invnD[(size_t)f * NEMB + idx];
    int    bi = idx;
#pragma unroll
    for (int m = 8; m <= 32; m <<= 1) {
        double ov = __shfl_xor(bv, m, 64);
        int    oi = __shfl_xor(bi, m, 64);
        if (ov > bv || (ov == bv && oi < bi)) { bv = ov; bi = oi; }
    }
    if (lane == 0) out[task] = bi;
}

// ---------------- launch ----------------
extern "C" void kernel_launch(void* const* d_in, const int* in_sizes, int n_in,
                              void* d_out, int out_size, void* d_ws, size_t ws_size,
                              hipStream_t stream)
{
    const float* x     = (const float*)d_in[0];
    const float* projA = (const float*)d_in[1];
    const float* projP = (const float*)d_in[2];
    const float* cbA   = (const float*)d_in[3];
    const float* cbP   = (const float*)d_in[4];

    char* ws = (char*)d_ws;
    unsigned short* ftH   = (unsigned short*)(ws + OFF_FTH);
    unsigned short* ftL   = (unsigned short*)(ws + OFF_FTL);
    unsigned short* cbHp  = (unsigned short*)(ws + OFF_CBH);
    unsigned short* cbLp  = (unsigned short*)(ws + OFF_CBL);
    float*          featF = (float*)(ws + OFF_FD);
    double*         invnD = (double*)(ws + OFF_INV);
    int*            pi1   = (int*)(ws + OFF_PI1);
    int*            pi2   = (int*)(ws + OFF_PI2);

    dft_cb_kernel<<<DFT_BLOCKS + 256, 256, 0, stream>>>(
        x, projA, projP, cbA, cbP, ftH, ftL, featF, cbHp, cbLp, invnD);
    argmax_kernel<<<dim3(ROWS / 128, 2, 4), 256, 0, stream>>>(ftH, ftL, cbHp, cbLp, pi1, pi2);
    rescore_kernel<<<(2 * ROWS) / 4, 256, 0, stream>>>(featF, invnD, cbA, cbP, pi1, pi2, (int*)d_out);
}

// Round 8
// 265.227 us; speedup vs baseline: 1.2712x; 1.1572x over previous
//
#include <hip/hip_runtime.h>
#include <math.h>

// Problem constants
constexpr int ROWS  = 19456;   // B*C*N = 16*19*64
constexpr int IN_DIM = 200;
constexpr int FREQ  = 101;     // rfft bins
constexpr int VQD   = 64;
constexpr int NEMB  = 8192;
constexpr int DFT_BLOCKS = ROWS / 8;   // 2432

typedef __attribute__((ext_vector_type(8))) short short8;   // 8 bf16 = 4 VGPRs
typedef __attribute__((ext_vector_type(4))) float floatx4;

__device__ __forceinline__ unsigned short f2bf(float v) {   // RTN-even fp32->bf16
    unsigned int u = __builtin_bit_cast(unsigned int, v);
    unsigned int r = u + 0x7fffu + ((u >> 16) & 1u);
    return (unsigned short)(r >> 16);
}
__device__ __forceinline__ float bf2f(unsigned short b) {
    unsigned int u = ((unsigned int)b) << 16;
    return __builtin_bit_cast(float, u);
}

// cis(-2*pi*r/200) with exact quarter points (bitwise-identical to the r1-validated table)
__device__ __forceinline__ void cis_exact(int r, double& c, double& s) {
    if (r == 0)        { c =  1.0; s =  0.0; }
    else if (r == 50)  { c =  0.0; s = -1.0; }
    else if (r == 100) { c = -1.0; s =  0.0; }
    else if (r == 150) { c =  0.0; s =  1.0; }
    else {
        double ang = -6.283185307179586476925286766559 * (double)r / (double)IN_DIM;
        c = cos(ang); s = sin(ang);
    }
}

// async global->LDS DMA, 16 B per lane; LDS dest = wave-uniform base + lane*16
#define GLOAD_LDS(gp, lp) __builtin_amdgcn_global_load_lds( \
    (const __attribute__((address_space(1))) unsigned int*)(gp), \
    (__attribute__((address_space(3))) unsigned int*)(lp), 16, 0, 0)

// ---------------- workspace layout ----------------
constexpr size_t align256(size_t x) { return (x + 255) & ~(size_t)255; }
constexpr size_t SZ_FB    = (size_t)2 * ROWS * VQD * sizeof(unsigned short); // bf16 feats [2][ROWS][64]
constexpr size_t OFF_FTH  = 0;
constexpr size_t OFF_FTL  = align256(OFF_FTH + SZ_FB);
constexpr size_t SZ_CBB   = (size_t)2 * NEMB * VQD * sizeof(unsigned short); // bf16 codes [2][8192][64]
constexpr size_t OFF_CBH  = align256(OFF_FTL + SZ_FB);
constexpr size_t OFF_CBL  = align256(OFF_CBH + SZ_CBB);
constexpr size_t SZ_FD    = (size_t)2 * ROWS * VQD * sizeof(double);         // feat slot (f32, oversized ok)
constexpr size_t OFF_FD   = align256(OFF_CBL + SZ_CBB);
constexpr size_t SZ_INV   = (size_t)2 * NEMB * sizeof(double);               // f64 1/||cb||
constexpr size_t OFF_INV  = align256(OFF_FD + SZ_FD);
constexpr size_t SZ_PI    = (size_t)2 * 4 * ROWS * sizeof(int);              // top-2 per 2048-chunk
constexpr size_t OFF_PI1  = align256(OFF_INV + SZ_INV);
constexpr size_t OFF_PI2  = align256(OFF_PI1 + SZ_PI);

// ---------------- 1. fused DFT/proj (blocks < 2432) + cb_prep (blocks >= 2432) ----------------
// r25: dft_cb unchanged from r4/r24 (radix-4, plain launch_bounds, f32 featF).
// LDS plan (20064 B):
//   [    0,  7200) xsT  f32 [n=200][r] stride 9
//   [ 7200,  8800) e0   f32 [50][8]   x0+x2+x1+x3   (q=0)
//   [ 8800, 10400) e2   f32 [50][8]   x0+x2-x1-x3   (q=2)
//   [10400, 12000) d02  f32 [50][8]   x0-x2         (q=1,3 re)
//   [12000, 13600) d13  f32 [50][8]   x3-x1         (q=1,3 im)
//   [13600, 16832) reS  f32 [k][8]: cisT (f64[101][2]) -> bgrp1 re -> final re -> amp
//   [16832, 20064) imS  f32 [k][8]: bgrp1 im -> final im -> phase
//   projection phase: accS f32 [128][8] aliases e0 base (e-arrays dead after loop)
__global__ __launch_bounds__(256) void dft_cb_kernel(
    const float* __restrict__ x, const float* __restrict__ projA, const float* __restrict__ projP,
    const float* __restrict__ cbA, const float* __restrict__ cbP,
    unsigned short* __restrict__ ftH, unsigned short* __restrict__ ftL, float* __restrict__ featF,
    unsigned short* __restrict__ cbH, unsigned short* __restrict__ cbL, double* __restrict__ invnD)
{
    __shared__ __align__(16) char smem[20064];
    const int tid = threadIdx.x;

    if (blockIdx.x >= DFT_BLOCKS) {
        // ---- cb_prep body (validated rounds 5-16, unchanged) ----
        float* tile = (float*)smem;            // 64*65*4 = 16640 B
        float* inv  = (float*)(smem + 16640);  // 256 B
        const int bid2 = blockIdx.x - DFT_BLOCKS;
        const int which = bid2 >> 7;
        const int m0 = (bid2 & 127) * 64;
        const float* cb = which ? cbP : cbA;
        for (int e = tid; e < 4096; e += 256) {
            int c = e >> 6, d = e & 63;
            tile[c * 65 + d] = cb[(size_t)(m0 + c) * VQD + d];
        }
        __syncthreads();
        if (tid < 64) {
            double s = 0.0;
            for (int d2 = 0; d2 < 64; ++d2) { double v = (double)tile[tid * 65 + d2]; s += v * v; }
            inv[tid] = (float)(1.0 / sqrt(s));
            invnD[(size_t)which * NEMB + m0 + tid] = 1.0 / sqrt(s);
        }
        __syncthreads();
        for (int e = tid; e < 4096; e += 256) {
            int c = e >> 6, d = e & 63;
            float v = tile[c * 65 + d] * inv[c];
            unsigned short hb = f2bf(v);
            unsigned short lb = f2bf(v - bf2f(hb));
            size_t o = ((size_t)which * NEMB + m0 + c) * VQD + d;
            cbH[o] = hb; cbL[o] = lb;
        }
        return;
    }

    float*  xsT  = (float*)smem;                 // [n][r] stride 9
    float*  e0S  = (float*)(smem + 7200);        // [50][8]
    float*  e2S  = (float*)(smem + 8800);
    float*  d02S = (float*)(smem + 10400);
    float*  d13S = (float*)(smem + 12000);
    float*  reS  = (float*)(smem + 13600);       // [k][8]
    float*  imS  = (float*)(smem + 16832);
    double* cisT = (double*)(smem + 13600);      // f64[101][2] = 1616 B, aliases reS (dead)
    float*  accS = (float*)(smem + 7200);        // proj partials, after e-arrays die
    const int r0 = blockIdx.x * 8;

    for (int e = tid; e < 8 * IN_DIM; e += 256) {
        int r = e / IN_DIM, n = e - r * IN_DIM;
        xsT[n * 9 + r] = x[(size_t)(r0 + r) * IN_DIM + n];
    }
    __syncthreads();

    // radix-4 prep: 4-point DFT over a (n = 50a+b), adds only, f32
    for (int e = tid; e < 50 * 8; e += 256) {
        int b = e >> 3, r = e & 7;
        float x0 = xsT[b * 9 + r];
        float x1 = xsT[(50 + b) * 9 + r];
        float x2 = xsT[(100 + b) * 9 + r];
        float x3 = xsT[(150 + b) * 9 + r];
        float s02 = x0 + x2, dd02 = x0 - x2;
        float s13 = x1 + x3, dd13 = x3 - x1;
        e0S[e]  = s02 + s13;
        e2S[e]  = s02 - s13;
        d02S[e] = dd02;
        d13S[e] = dd13;
    }
    // cis table: one f64 sincos per k, computed once per block (2 wave-calls)
    if (tid < FREQ) {
        double c, s;
        cis_exact(tid, c, s);
        cisT[tid * 2]     = c;
        cisT[tid * 2 + 1] = s;
    }
    __syncthreads();

    // q-homogeneous wave mapping: parity = wave&1 selects k parity; bgrp = wave>>1
    const int lane = tid & 63, wv = tid >> 6;
    const int parity = wv & 1, bgrp = wv >> 1;
    const int k = 2 * lane + parity;
    const bool act = (k < FREQ);                 // even wave: 51 lanes, odd: 50

    double c1 = 1.0, s1 = 0.0, wc = 1.0, ws = 0.0;
    if (act) {
        c1 = cisT[k * 2]; s1 = cisT[k * 2 + 1];
        if (bgrp) {
            // start twiddle W^{25k} = e^{-i pi (k&7)/4}: exact eighth points
            const double RH = 0.70710678118654752440;
            switch (k & 7) {
                case 0:  wc =  1.0; ws =  0.0; break;
                case 1:  wc =  RH;  ws = -RH;  break;
                case 2:  wc =  0.0; ws = -1.0; break;
                case 3:  wc = -RH;  ws = -RH;  break;
                case 4:  wc = -1.0; ws =  0.0; break;
                case 5:  wc = -RH;  ws =  RH;  break;
                case 6:  wc =  0.0; ws =  1.0; break;
                default: wc =  RH;  ws =  RH;  break;
            }
        }
    }
    __syncthreads();   // seals cisT before bgrp1's reS stores (table now dead)

    float re[8], im[8];
    if (act) {
#pragma unroll
        for (int r = 0; r < 8; ++r) { re[r] = 0.f; im[r] = 0.f; }
        const int b0 = bgrp * 25;
        if (parity == 0) {
            // even k: Y real = e0 (q=0) or e2 (q=2); 2 FMA/r, 2 b128/iter
            const float* Y = (k & 2) ? e2S : e0S;
            for (int j = 0; j < 25; ++j) {
                const float* Yb = Y + (b0 + j) * 8;
                float wcf = (float)wc, wsf = (float)ws;
#pragma unroll
                for (int r = 0; r < 8; ++r) {
                    float y = Yb[r];
                    re[r] = fmaf(y, wcf, re[r]);
                    im[r] = fmaf(y, wsf, im[r]);
                }
                double nwc = fma(wc, c1, -ws * s1);
                double nws = fma(wc, s1,  ws * c1);
                wc = nwc; ws = nws;
            }
        } else {
            // odd k: Y = d02 + i*t*d13, t=+1 (q=1) / -1 (q=3); 4 FMA/r, 4 b128/iter
            const float tq = (k & 2) ? -1.f : 1.f;
            for (int j = 0; j < 25; ++j) {
                const float* Ar = d02S + (b0 + j) * 8;
                const float* Ai = d13S + (b0 + j) * 8;
                float wcf = (float)wc, wsf = (float)ws;
                float u = tq * wcf, v = tq * wsf;
#pragma unroll
                for (int r = 0; r < 8; ++r) {
                    float ar = Ar[r], ai = Ai[r];
                    re[r] = fmaf(ar, wcf, re[r]);
                    re[r] = fmaf(ai, -v,  re[r]);
                    im[r] = fmaf(ar, wsf, im[r]);
                    im[r] = fmaf(ai, u,   im[r]);
                }
                double nwc = fma(wc, c1, -ws * s1);
                double nws = fma(wc, s1,  ws * c1);
                wc = nwc; ws = nws;
            }
        }
        if (bgrp == 1) {
#pragma unroll
            for (int r = 0; r < 8; ++r) { reS[k * 8 + r] = re[r]; imS[k * 8 + r] = im[r]; }
        }
    }
    __syncthreads();
    // combine b-groups (each k owned by exactly one bgrp0 thread)
    if (bgrp == 0 && act) {
#pragma unroll
        for (int r = 0; r < 8; ++r) {
            re[r] += reS[k * 8 + r]; im[r] += imS[k * 8 + r];
            reS[k * 8 + r] = re[r];  imS[k * 8 + r] = im[r];
        }
    }
    __syncthreads();
    // amp/phase on ALL 256 threads, f32 fast path; rare exact-f64 fallback for small bins
    // (xsT still alive -> fallback recomputes the bin from the exact f32 inputs)
    for (int e = tid; e < FREQ * 8; e += 256) {
        float c = reS[e], s = imS[e];
        float a2 = fmaf(c, c, s * s);
        float ampv, phv;
        if (a2 >= 0.04f) {
            ampv = sqrtf(a2);
            phv  = atan2f(s, c);
        } else {
            const int kk = e >> 3, rr = e & 7;
            double sg = (kk & 1) ? -1.0 : 1.0;
            double reD = (double)xsT[rr] + sg * (double)xsT[100 * 9 + rr];
            double imD = 0.0;
            double cc1, ss1;
            cis_exact(kk, cc1, ss1);
            double twc = cc1, tws = ss1;             // w at n=1
            for (int n = 1; n < 100; ++n) {
                double a = (double)xsT[n * 9 + rr];
                double b = (double)xsT[(IN_DIM - n) * 9 + rr];
                reD = fma(a + b, twc, reD);
                imD = fma(a - b, tws, imD);
                double nwc = fma(twc, cc1, -tws * ss1);
                double nws = fma(twc, ss1,  tws * cc1);
                twc = nwc; tws = nws;
            }
            ampv = (float)sqrt(reD * reD + imD * imD);
            phv  = (float)atan2(imD, reD);
        }
        reS[e] = ampv; imS[e] = phv;
    }
    __syncthreads();

    // projection in f32: d = tid&63; which = amp/phase; grp splits kk range 51/50
    const int d = tid & 63, which = (tid >> 6) & 1, grp = tid >> 7;
    const float* proj = which ? projP : projA;
    const float* srcF = which ? imS : reS;          // [k][8], k-major
    float acc[8];
#pragma unroll
    for (int r = 0; r < 8; ++r) acc[r] = 0.f;
    const int kkA = grp ? 51 : 0;
    const int kkB = grp ? FREQ : 51;
    for (int kk = kkA; kk < kkB; ++kk) {
        float p = proj[kk * VQD + d];
#pragma unroll
        for (int r = 0; r < 8; ++r) acc[r] = fmaf(srcF[kk * 8 + r], p, acc[r]);
    }
    if (grp) {
#pragma unroll
        for (int r = 0; r < 8; ++r) accS[(tid & 127) * 8 + r] = acc[r];
    }
    __syncthreads();
    if (grp == 0) {
#pragma unroll
        for (int r = 0; r < 8; ++r) acc[r] += accS[tid * 8 + r];
#pragma unroll
        for (int r = 0; r < 8; ++r) {
            size_t rowi = (size_t)which * ROWS + r0 + r;
            float vf = acc[r];
            unsigned short hb = f2bf(vf);
            unsigned short lb = f2bf(vf - bf2f(hb));
            ftH[rowi * VQD + d] = hb;
            ftL[rowi * VQD + d] = lb;
            featF[rowi * VQD + d] = vf;
        }
    }
}

// ---------------- 2. bf16x3 MFMA sim + top-2, DMA double-buffered prefetch ----------------
// r25: UPD REVERTED to the original r4-validated 8-op cndmask form. The med3+fmax
// rewrite (r23/r24) regressed 156->200 us: VGPR 60->68, MfmaUtil 34->26 — in an
// issue-saturated kernel the compiler's compare-reuse + liveness mattered more than
// the op count. Do not reintroduce without disasm evidence.
#define MFMA(a, b, c) __builtin_amdgcn_mfma_f32_16x16x32_bf16(a, b, c, 0, 0, 0)
#define UPD(val, s) do { float _v = (val); \
    bool _c1 = _v > b1v[s]; bool _c2 = _v > b2v[s]; \
    b2v[s] = _c1 ? b1v[s] : (_c2 ? _v : b2v[s]); \
    b2i[s] = _c1 ? b1i[s] : (_c2 ? idx : b2i[s]); \
    b1v[s] = _c1 ? _v : b1v[s]; \
    b1i[s] = _c1 ? idx : b1i[s]; } while (0)

__global__ __launch_bounds__(256, 3) void argmax_kernel(
    const unsigned short* __restrict__ ftH, const unsigned short* __restrict__ ftL,
    const unsigned short* __restrict__ cbH, const unsigned short* __restrict__ cbL,
    int* __restrict__ pi1, int* __restrict__ pi2)
{
    __shared__ __align__(16) char lds[33792];
    const int tid = threadIdx.x;
    const int f = blockIdx.y, z = blockIdx.z;
    const int r0 = blockIdx.x * 128;
    const int w = tid >> 6, lane = tid & 63;
    const int q = lane >> 4, cl = lane & 15;

    const unsigned short* ftHb = ftH + (size_t)f * ROWS * VQD;
    const unsigned short* ftLb = ftL + (size_t)f * ROWS * VQD;
    const unsigned short* cbHb = cbH + (size_t)f * NEMB * VQD;
    const unsigned short* cbLb = cbL + (size_t)f * NEMB * VQD;

    short8 aH00, aH01, aH10, aH11, aL00, aL01, aL10, aL11;
    {
        const size_t baseA = (size_t)(r0 + w * 32 + cl) * VQD + q * 8;
        const size_t baseB = baseA + (size_t)16 * VQD;
        aH00 = *(const short8*)(ftHb + baseA);
        aH01 = *(const short8*)(ftHb + baseA + 32);
        aH10 = *(const short8*)(ftHb + baseB);
        aH11 = *(const short8*)(ftHb + baseB + 32);
        aL00 = *(const short8*)(ftLb + baseA);
        aL01 = *(const short8*)(ftLb + baseA + 32);
        aL10 = *(const short8*)(ftLb + baseB);
        aL11 = *(const short8*)(ftLb + baseB + 32);
    }

    float b1v[8], b2v[8]; int b1i[8], b2i[8];
#pragma unroll
    for (int s = 0; s < 8; ++s) { b1v[s] = -INFINITY; b2v[s] = -INFINITY; b1i[s] = 0; b2i[s] = 0; }

    const int cBase = tid >> 3;
    const int jel   = (((tid & 7) ^ (cBase & 7)) << 3);
    const unsigned short* gH = cbHb + (size_t)(z * 2048 + cBase) * VQD + jel;
    const unsigned short* gL = cbLb + (size_t)(z * 2048 + cBase) * VQD + jel;

    const int p0 = ((q ^ (cl & 7)) << 4);
    const int p1 = p0 ^ 64;

#pragma unroll
    for (int r = 0; r < 2; ++r) {
        const size_t gofs = (size_t)(32 * r) * VQD;
        GLOAD_LDS(gH + gofs, lds + w * 1024 + r * 4096);
        GLOAD_LDS(gL + gofs, lds + 8192 + w * 1024 + r * 4096);
    }

    for (int it = 0; it < 32; ++it) {
        __syncthreads();
        if (it < 31) {
            char* nbuf = lds + ((it + 1) & 1) * 16384;
            const size_t gbase = (size_t)((it + 1) * 64) * VQD;
#pragma unroll
            for (int r = 0; r < 2; ++r) {
                const size_t gofs = gbase + (size_t)(32 * r) * VQD;
                GLOAD_LDS(gH + gofs, nbuf + w * 1024 + r * 4096);
                GLOAD_LDS(gL + gofs, nbuf + 8192 + w * 1024 + r * 4096);
            }
        }

        const char* buf = lds + (it & 1) * 16384;
        const int cbase = z * 2048 + it * 64;
#pragma unroll
        for (int nt = 0; nt < 4; ++nt) {
            const char* row = buf + (nt * 16 + cl) * 128;
            short8 bH0 = *(const short8*)(row + p0);
            short8 bH1 = *(const short8*)(row + p1);
            short8 bL0 = *(const short8*)(row + 8192 + p0);
            short8 bL1 = *(const short8*)(row + 8192 + p1);

            floatx4 acc0 = {0.f, 0.f, 0.f, 0.f};
            floatx4 acc1 = {0.f, 0.f, 0.f, 0.f};
            acc0 = MFMA(aH00, bH0, acc0);  acc1 = MFMA(aH10, bH0, acc1);
            acc0 = MFMA(aH01, bH1, acc0);  acc1 = MFMA(aH11, bH1, acc1);
            acc0 = MFMA(aH00, bL0, acc0);  acc1 = MFMA(aH10, bL0, acc1);
            acc0 = MFMA(aH01, bL1, acc0);  acc1 = MFMA(aH11, bL1, acc1);
            acc0 = MFMA(aL00, bH0, acc0);  acc1 = MFMA(aL10, bH0, acc1);
            acc0 = MFMA(aL01, bH1, acc0);  acc1 = MFMA(aL11, bH1, acc1);

            const int idx = cbase + nt * 16 + cl;
#pragma unroll
            for (int i = 0; i < 4; ++i) { UPD(acc0[i], i); UPD(acc1[i], 4 + i); }
        }
    }

    __syncthreads();
    float* redv = (float*)lds;           // [128][33]
    int*   redi = (int*)(lds + 128 * 33 * 4);
#pragma unroll
    for (int s = 0; s < 8; ++s) {
        int rowl = w * 32 + ((s & 4) << 2) + q * 4 + (s & 3);   // +16 when s>=4
        int base = rowl * 33 + cl * 2;
        redv[base]     = b1v[s]; redi[base]     = b1i[s];
        redv[base + 1] = b2v[s]; redi[base + 1] = b2i[s];
    }
    __syncthreads();
    if (tid < 128) {
        float v1 = -INFINITY, v2 = -INFINITY; int i1 = 0x7fffffff, i2 = 0x7fffffff;
        for (int e = 0; e < 32; ++e) {
            float v = redv[tid * 33 + e]; int id = redi[tid * 33 + e];
            if (v > v1 || (v == v1 && id < i1)) { v2 = v1; i2 = i1; v1 = v; i1 = id; }
            else if (v > v2 || (v == v2 && id < i2)) { v2 = v; i2 = id; }
        }
        size_t p = ((size_t)(f * 4 + z)) * ROWS + r0 + tid;
        pi1[p] = i1; pi2[p] = i2;
    }
}

// ---------------- 3. f64 rescore of the 8 candidates/row (r19 structure; f32 feat input,
// upcast exactly -> bitwise-identical rescoring) ----------------
__global__ __launch_bounds__(256) void rescore_kernel(
    const float* __restrict__ featF, const double* __restrict__ invnD,
    const float* __restrict__ cbA, const float* __restrict__ cbP,
    const int* __restrict__ pi1, const int* __restrict__ pi2,
    int* __restrict__ out)
{
    const int tid = threadIdx.x;
    const int lane = tid & 63, wave = tid >> 6;
    const int task = blockIdx.x * 4 + wave;           // 0 .. 2*ROWS-1
    const int f = task / ROWS;
    const int row = task - f * ROWS;
    const float* cb = f ? cbP : cbA;

    const int c  = lane >> 3;        // candidate 0..7
    const int dp = (lane & 7) * 8;   // d-slice base

    const int zz = c >> 1;
    const size_t p = ((size_t)(f * 4 + zz)) * ROWS + row;
    const int idx = (c & 1) ? pi2[p] : pi1[p];

    const float* fr = featF + ((size_t)f * ROWS + row) * VQD + dp;
    const float* cr = cb + (size_t)idx * VQD + dp;
    double t = 0.0;
#pragma unroll
    for (int j = 0; j < 8; ++j) t = fma((double)fr[j], (double)cr[j], t);
    t += __shfl_xor(t, 1, 64);
    t += __shfl_xor(t, 2, 64);
    t += __shfl_xor(t, 4, 64);
    double bv = t * invnD[(size_t)f * NEMB + idx];
    int    bi = idx;
#pragma unroll
    for (int m = 8; m <= 32; m <<= 1) {
        double ov = __shfl_xor(bv, m, 64);
        int    oi = __shfl_xor(bi, m, 64);
        if (ov > bv || (ov == bv && oi < bi)) { bv = ov; bi = oi; }
    }
    if (lane == 0) out[task] = bi;
}

// ---------------- launch ----------------
extern "C" void kernel_launch(void* const* d_in, const int* in_sizes, int n_in,
                              void* d_out, int out_size, void* d_ws, size_t ws_size,
                              hipStream_t stream)
{
    const float* x     = (const float*)d_in[0];
    const float* projA = (const float*)d_in[1];
    const float* projP = (const float*)d_in[2];
    const float* cbA   = (const float*)d_in[3];
    const float* cbP   = (const float*)d_in[4];

    char* ws = (char*)d_ws;
    unsigned short* ftH   = (unsigned short*)(ws + OFF_FTH);
    unsigned short* ftL   = (unsigned short*)(ws + OFF_FTL);
    unsigned short* cbHp  = (unsigned short*)(ws + OFF_CBH);
    unsigned short* cbLp  = (unsigned short*)(ws + OFF_CBL);
    float*          featF = (float*)(ws + OFF_FD);
    double*         invnD = (double*)(ws + OFF_INV);
    int*            pi1   = (int*)(ws + OFF_PI1);
    int*            pi2   = (int*)(ws + OFF_PI2);

    dft_cb_kernel<<<DFT_BLOCKS + 256, 256, 0, stream>>>(
        x, projA, projP, cbA, cbP, ftH, ftL, featF, cbHp, cbLp, invnD);
    argmax_kernel<<<dim3(ROWS / 128, 2, 4), 256, 0, stream>>>(ftH, ftL, cbHp, cbLp, pi1, pi2);
    rescore_kernel<<<(2 * ROWS) / 4, 256, 0, stream>>>(featF, invnD, cbA, cbP, pi1, pi2, (int*)d_out);
}